// Round 21
// baseline (51.689 us; speedup 1.0000x reference)
//
#include <hip/hip_runtime.h>

#define NPIX (512*512)   // 262144
#define NROWS 32         // 8 images x 4 channels
#define NBIN 256         // half-octave bins: code>>6 of (f32bits>>16); v<1 => bin<=254
#define HSTR 1026        // copy stride in words: 1026 % 32 = 2 -> the 8 copies
                         // of a bin land in 8 DISTINCT banks (R20 lesson)

// RTNE round of f32 to its top-16 bits. Monotone in v for v>=0.
__device__ inline unsigned rtne16_(float v){
  unsigned u = __float_as_uint(v);
  return (u + 0x7FFFu + ((u>>16)&1u)) >> 16;
}

__device__ inline float wredf_(float v){
  #pragma unroll
  for (int o=32;o>0;o>>=1) v += __shfl_down(v, o);
  return v;
}

// ---------------------------------------------------------------------------
// MEGA PASS v10 — phase-diversity experiment.
// R20 state: no pipe saturated (VALU 29%, LDS conflicts fixed, HBM 16%),
// residual = phase lockstep of 2 barrier-synced 1024-thr blocks per CU.
// This round: 512-thr blocks (grid 1024) -> 4 independent barrier domains
// per CU at the same 32-wave cap. Keeps: packed single u32 atomic
// ((1<<21)|fx), bank-padded 8-copy histogram (stride 1026), fast-math,
// 12-load batch, one-pass flush.
// Capacity: <=64 thr/copy x 16 elems = 1024 elems x fx<=1024 -> sum < 2^21.
// segacc: [0]=bce1 [1]=bce2 [2..9]=i1 [10..17]=x1 [18..25]=t1
//         [26..33]=i2 [34..41]=x2 [42..49]=t2
// ---------------------------------------------------------------------------
__global__ __launch_bounds__(512, 8) void k_mega(
  const float* __restrict__ us, const float* __restrict__ inputs,
  const float* __restrict__ train_mask, const float* __restrict__ tr_mask,
  const float* __restrict__ label,
  unsigned* __restrict__ ghc, float* __restrict__ ghs,
  float* __restrict__ pos_cf, float* __restrict__ pos_s,
  float* __restrict__ segacc)
{
  __shared__ unsigned s_hist[8*HSTR];     // [copy(8)][ch][bin] packed, 32.8KB
  int tid = threadIdx.x;
  for (int j=tid;j<8*HSTR;j+=512) s_hist[j]=0u;
  __syncthreads();

  int img = blockIdx.x>>7, chunk = blockIdx.x&127;
  int cpy = (tid&7)*HSTR;

  int p0 = chunk*2048 + tid*4;                 // coalesced: lane-stride 16B
  size_t gp = (size_t)img*NPIX + p0;

  // ---- 12 independent dwordx4 loads ----
  float4 tm4 = *(const float4*)(train_mask + gp);
  float4 lb4 = *(const float4*)(label + gp);
  const float4* t16 = (const float4*)(tr_mask + gp*4);
  float4 tv0 = t16[0], tv1 = t16[1], tv2 = t16[2], tv3 = t16[3];
  float4 xc0 = *(const float4*)(inputs + ((size_t)(img*4+0))*NPIX + p0);
  float4 xc1 = *(const float4*)(inputs + ((size_t)(img*4+1))*NPIX + p0);
  float4 xc2 = *(const float4*)(inputs + ((size_t)(img*4+2))*NPIX + p0);
  float4 xc3 = *(const float4*)(inputs + ((size_t)(img*4+3))*NPIX + p0);
  float4 ua4 = *(const float4*)(us + ((size_t)img*2  )*NPIX + p0);
  float4 ub4 = *(const float4*)(us + ((size_t)img*2+1)*NPIX + p0);

  float tm[4] = {tm4.x,tm4.y,tm4.z,tm4.w};
  float lb[4] = {lb4.x,lb4.y,lb4.z,lb4.w};
  float ta_[16] = {tv0.x,tv0.y,tv0.z,tv0.w, tv1.x,tv1.y,tv1.z,tv1.w,
                   tv2.x,tv2.y,tv2.z,tv2.w, tv3.x,tv3.y,tv3.z,tv3.w};
  float xs_[16] = {xc0.x,xc0.y,xc0.z,xc0.w, xc1.x,xc1.y,xc1.z,xc1.w,
                   xc2.x,xc2.y,xc2.z,xc2.w, xc3.x,xc3.y,xc3.z,xc3.w};

  float pcf[4]={0,0,0,0}, ps[4]={0,0,0,0};
  unsigned zc[4]={0,0,0,0};
  float bce1=0.f, i1=0.f, x1s=0.f, t1s=0.f;
  float bce2=0.f, i2=0.f, x2s=0.f, t2s=0.f;

  #pragma unroll
  for (int ch=0; ch<4; ++ch){
    #pragma unroll
    for (int j=0;j<4;++j){
      float t = ta_[j*4+ch];
      float x = xs_[ch*4+j];
      float E = __expf(-fabsf(x));               // native v_exp
      float r = __builtin_amdgcn_rcpf(1.f+E);    // sigmoid(|x|)
      float s = (x>=0.f)? r : 1.f-r;             // sigmoid(x)
      float d = s - t;
      float v = d*d*tm[j];                       // pre_loss in [0,1)
      if (t >= 0.001f){ pcf[ch]+=1.f; ps[ch]+=v; }
      else {
        unsigned code = rtne16_(v);              // <= 0x3F80
        if (code == 0u) zc[ch]++;                // zero-class: registers
        else {
          unsigned fx = (unsigned)(v*1024.f + 0.5f);       // <= 1024
          atomicAdd(&s_hist[cpy + ch*NBIN + (int)(code>>6)],
                    (1u<<21) | fx);              // ONE packed u32 atomic
        }
      }
      if (ch==3){                                // seg2: last ch vs label
        float tt = lb[j];
        bce2 += fmaxf(x,0.f) - x*tt + __logf(1.f+E);
        i2 += s*tt; x2s += s; t2s += tt;
      }
    }
  }

  { // seg1: us channels vs one-hot(label)
    float aa[4]={ua4.x,ua4.y,ua4.z,ua4.w};
    float bb[4]={ub4.x,ub4.y,ub4.z,ub4.w};
    #pragma unroll
    for (int j=0;j<4;++j){
      float t1 = lb[j], t0 = 1.f - t1;
      float x0=aa[j], x1=bb[j];
      float E0 = __expf(-fabsf(x0)), E1 = __expf(-fabsf(x1));
      float r0 = __builtin_amdgcn_rcpf(1.f+E0);
      float r1 = __builtin_amdgcn_rcpf(1.f+E1);
      float s0 = (x0>=0.f)? r0 : 1.f-r0;
      float s1 = (x1>=0.f)? r1 : 1.f-r1;
      bce1 += fmaxf(x0,0.f) - x0*t0 + __logf(1.f+E0);
      bce1 += fmaxf(x1,0.f) - x1*t1 + __logf(1.f+E1);
      i1 += s0*t0 + s1*t1; x1s += s0+s1; t1s += t0+t1;
    }
  }

  #pragma unroll
  for (int ch=0;ch<4;++ch)
    if (zc[ch]) atomicAdd(&s_hist[cpy + ch*NBIN], zc[ch]<<21); // bin0: cnt only

  // 16-scalar block reduction (8 waves)
  __shared__ float s_red[8][16];
  float red[16] = {pcf[0],pcf[1],pcf[2],pcf[3], ps[0],ps[1],ps[2],ps[3],
                   bce1, i1, x1s, t1s, bce2, i2, x2s, t2s};
  int wid = tid>>6, lane = tid&63;
  #pragma unroll
  for (int q=0;q<16;++q){
    float r = wredf_(red[q]);
    if (lane==0) s_red[wid][q] = r;
  }
  __syncthreads();
  if (tid < 16){
    float tot = 0.f;
    #pragma unroll
    for (int w2=0;w2<8;++w2) tot += s_red[w2][tid];
    int q = tid;
    if      (q<4)   atomicAdd(&pos_cf[img*4+q], tot);
    else if (q<8)   atomicAdd(&pos_s[img*4+q-4], tot);
    else if (q==8)  atomicAdd(&segacc[0], tot);
    else if (q==9)  atomicAdd(&segacc[2+img], tot);
    else if (q==10) atomicAdd(&segacc[10+img], tot);
    else if (q==11) atomicAdd(&segacc[18+img], tot);
    else if (q==12) atomicAdd(&segacc[1], tot);
    else if (q==13) atomicAdd(&segacc[26+img], tot);
    else if (q==14) atomicAdd(&segacc[34+img], tot);
    else            atomicAdd(&segacc[42+img], tot);
  }

  // flush: 1024 bins over 512 threads (2 each), unpack 8 copies
  for (int j=tid;j<4*NBIN;j+=512){
    unsigned c=0u, fsum=0u;
    #pragma unroll
    for (int cp=0;cp<8;++cp){
      unsigned p = s_hist[cp*HSTR + j];
      c    += p>>21;
      fsum += p & 0x1FFFFFu;
    }
    int ch = j>>8, bin = j&255;
    if (c){
      atomicAdd(&ghc[(img*4+ch)*NBIN + bin], c);
      float s = (float)fsum * (1.f/1024.f);
      if (s!=0.f) atomicAdd(&ghs[(img*4+ch)*NBIN + bin], s);
    }
  }
}

// ---------------------------------------------------------------------------
// POST: items + scalar fused in ONE single-block launch (1024 threads).
// Each row owned by a 32-lane group (lane t: bins [t*8, t*8+8)); shfl-based
// suffix scan (width 32); owner lane applies the order-statistics boundary
// correction (R14..R20: absmax 0.0). Then wave 0 assembles the scalar.
// Output: (h<<16)|h dual f32/bf16 encoding (proven).
// ---------------------------------------------------------------------------
__global__ __launch_bounds__(1024) void k_post(
  const unsigned* __restrict__ ghc, const float* __restrict__ ghs,
  const float* __restrict__ pos_cf, const float* __restrict__ pos_s,
  const float* __restrict__ segacc, const float* __restrict__ swp,
  unsigned* __restrict__ out)
{
  __shared__ float s_items[NROWS];
  int tid = threadIdx.x;
  int row = tid >> 5, t32 = tid & 31;

  {
    unsigned pc = (unsigned)pos_cf[row];
    float psv = pos_s[row];
    unsigned neg = (unsigned)NPIX - pc, k3 = 3u*pc;
    unsigned k = pc ? (neg<k3?neg:k3) : 100u;   // pos==0 -> top-100 fallback

    unsigned bc[8]; float bsum=0.f; unsigned bcnt=0u;
    #pragma unroll
    for (int j=0;j<8;++j){
      int b = row*NBIN + t32*8 + j;
      bc[j] = ghc[b];
      bcnt += bc[j];
      bsum += ghs[b];
    }
    unsigned suf_c = bcnt; float suf_s = bsum;
    #pragma unroll
    for (int o=1;o<32;o<<=1){
      unsigned c2 = __shfl_down(suf_c, o, 32);
      float    s2 = __shfl_down(suf_s, o, 32);
      if (t32 + o < 32){ suf_c += c2; suf_s += s2; }
    }
    unsigned nxt_c = __shfl_down(suf_c, 1, 32);
    float    nxt_s = __shfl_down(suf_s, 1, 32);
    if (t32 == 31){ nxt_c = 0u; nxt_s = 0.f; }

    if (k == 0u){
      if (t32==0) s_items[row] = psv/(float)(pc?pc:1u);
    } else if (t32==0 && suf_c < k){
      float ssel = suf_s;                       // cut in zero-class tail
      s_items[row] = pc ? (psv/(float)pc + ssel/(float)k) : (ssel/100.f);
    } else if (nxt_c < k && suf_c >= k){        // owner lane
      unsigned cnt = nxt_c; float sum = nxt_s;
      int bin = -1; unsigned c0 = 1u; float sown = 0.f;
      for (int j=7;j>=0;--j){
        unsigned c = bc[j];
        if (!c) continue;
        if (cnt + c >= k){ bin = t32*8 + j; c0 = c;
                           sown = ghs[row*NBIN + bin]; break; }
        cnt += c; sum += ghs[row*NBIN + t32*8 + j];
      }
      unsigned rem = k - cnt;                   // 1 <= rem <= c0
      float mean = sown / (float)c0;
      float lo = __uint_as_float(((unsigned)bin<<6)<<16);
      float hi = __uint_as_float((((unsigned)bin+1u)<<6)<<16);
      float wdt = hi - lo;
      float mtop = mean + 0.5f*wdt*(1.f - (float)rem/(float)c0);
      mtop = fminf(fmaxf(mtop, lo), hi);        // safety clamp
      float ssel = sum + (float)rem * mtop;
      s_items[row] = pc ? (psv/(float)pc + ssel/(float)k) : (ssel/100.f);
    }
  }
  __syncthreads();
  if (tid >= 64) return;

  // ---- scalar assembly on wave 0 ----
  float v = (tid<NROWS)? s_items[tid] : 0.f;
  v = wredf_(v);                                 // lane 0 gets total
  if (tid != 0) return;

  double lsum = (double)v;
  double sw = (double)swp[0];
  double loss = (lsum/8.0)/(2.0*sw*sw + 1e-6) - log(sw);
  double d1=0.0, d2=0.0;
  for (int i=0;i<8;++i){
    d1 += (2.0*(double)segacc[2+i]  + 1e-5)/((double)segacc[10+i] + (double)segacc[18+i] + 1e-5);
    d2 += (2.0*(double)segacc[26+i] + 1e-5)/((double)segacc[34+i] + (double)segacc[42+i] + 1e-5);
  }
  double seg1 = 0.5*((double)segacc[0]/(2.0*8.0*(double)NPIX)) + (1.0 - d1/8.0);
  double seg2 = 0.5*((double)segacc[1]/(8.0*(double)NPIX))     + (1.0 - d2/8.0);
  float tot = (float)(seg1 + seg2 + loss);
  unsigned u = __float_as_uint(tot);
  unsigned h = (u + 0x7FFFu + ((u>>16)&1u)) >> 16;   // RTNE bf16 bits
  out[0] = (h<<16) | h;                               // dual f32/bf16 encoding
}

// ---------------------------------------------------------------------------
extern "C" void kernel_launch(void* const* d_in, const int* in_sizes, int n_in,
                              void* d_out, int out_size, void* d_ws, size_t ws_size,
                              hipStream_t stream)
{
  const float* us         = (const float*)d_in[0];  // (8,2,512,512)
  const float* inputs     = (const float*)d_in[1];  // (8,4,512,512)
  const float* train_mask = (const float*)d_in[2];  // (8,1,512,512)
  const float* tr_mask    = (const float*)d_in[3];  // (8,512,512,4)
  const float* label      = (const float*)d_in[4];  // (8,1,512,512)
  const float* sw         = (const float*)d_in[5];  // (1,)

  char* w = (char*)d_ws;
  size_t off = 0;
  unsigned* ghc   = (unsigned*)(w+off); off += (size_t)NROWS*NBIN*4;  // 32KB
  float*    ghs   = (float*)(w+off);    off += (size_t)NROWS*NBIN*4;  // 32KB
  float*    pos_cf= (float*)(w+off);    off += NROWS*4;
  float*    pos_s = (float*)(w+off);    off += NROWS*4;
  float*    segacc= (float*)(w+off);    off += 64*4;
  size_t zbytes = off;                               // ~66KB zeroed each call

  hipMemsetAsync(w, 0, zbytes, stream);

  k_mega <<<dim3(1024), dim3(512),  0, stream>>>(us, inputs, train_mask, tr_mask,
                                                 label, ghc, ghs,
                                                 pos_cf, pos_s, segacc);
  k_post <<<dim3(1),    dim3(1024), 0, stream>>>(ghc, ghs, pos_cf, pos_s,
                                                 segacc, sw, (unsigned*)d_out);
}

// Round 22
// 39.642 us; speedup vs baseline: 1.3039x; 1.3039x over previous
//
#include <hip/hip_runtime.h>

#define NPIX (512*512)   // 262144
#define NROWS 32         // 8 images x 4 channels
#define NBIN 256         // half-octave bins: code>>6 of (f32bits>>16); v<1 => bin<=254
#define HSTR 1026        // copy stride in words: 1026 % 32 = 2 -> 16 copies hit
                         // 16 DISTINCT banks for the same bin (R19 used 1024,
                         // which put ALL copies of a bin in ONE bank)

// RTNE round of f32 to its top-16 bits. Monotone in v for v>=0.
__device__ inline unsigned rtne16_(float v){
  unsigned u = __float_as_uint(v);
  return (u + 0x7FFFu + ((u>>16)&1u)) >> 16;
}

__device__ inline float wredf_(float v){
  #pragma unroll
  for (int o=32;o>0;o>>=1) v += __shfl_down(v, o);
  return v;
}

// ---------------------------------------------------------------------------
// MEGA PASS (R20 exact — best measured 40.0us total; R21's 512-thr phase-
// diversity experiment regressed and is reverted).
// Ingredients, each counter-verified: fast-math transcendentals (R8),
// 12-load coalesced batch (R10), in-LDS histogram w/ per-block global flush
// (R14), packed single u32 atomic (R18), 1024-thr/16-copy geometry (R19),
// bank-padded copy stride (R20: conflicts 2.6M -> 0.38M).
// grid: 8 img x 64 chunks = 512 blocks x 1024 thr; 4 consecutive pos/thread.
// Pack: (1<<21)|fx, fx=round(v*1024): per copy <=1024 elems * fx<=1024 =
// 2^20 < 2^21 -- no overflow into the count field.
// segacc: [0]=bce1 [1]=bce2 [2..9]=i1 [10..17]=x1 [18..25]=t1
//         [26..33]=i2 [34..41]=x2 [42..49]=t2
// ---------------------------------------------------------------------------
__global__ __launch_bounds__(1024, 2) void k_mega(
  const float* __restrict__ us, const float* __restrict__ inputs,
  const float* __restrict__ train_mask, const float* __restrict__ tr_mask,
  const float* __restrict__ label,
  unsigned* __restrict__ ghc, float* __restrict__ ghs,
  float* __restrict__ pos_cf, float* __restrict__ pos_s,
  float* __restrict__ segacc)
{
  __shared__ unsigned s_hist[16*HSTR];    // [copy(16)][ch][bin] packed, 65.7KB
  int tid = threadIdx.x;
  for (int j=tid;j<16*HSTR;j+=1024) s_hist[j]=0u;
  __syncthreads();

  int img = blockIdx.x>>6, chunk = blockIdx.x&63;
  int cpy = (tid&15)*HSTR;

  int p0 = chunk*4096 + tid*4;                 // coalesced: lane-stride 16B
  size_t gp = (size_t)img*NPIX + p0;

  // ---- 12 independent dwordx4 loads ----
  float4 tm4 = *(const float4*)(train_mask + gp);
  float4 lb4 = *(const float4*)(label + gp);
  const float4* t16 = (const float4*)(tr_mask + gp*4);
  float4 tv0 = t16[0], tv1 = t16[1], tv2 = t16[2], tv3 = t16[3];
  float4 xc0 = *(const float4*)(inputs + ((size_t)(img*4+0))*NPIX + p0);
  float4 xc1 = *(const float4*)(inputs + ((size_t)(img*4+1))*NPIX + p0);
  float4 xc2 = *(const float4*)(inputs + ((size_t)(img*4+2))*NPIX + p0);
  float4 xc3 = *(const float4*)(inputs + ((size_t)(img*4+3))*NPIX + p0);
  float4 ua4 = *(const float4*)(us + ((size_t)img*2  )*NPIX + p0);
  float4 ub4 = *(const float4*)(us + ((size_t)img*2+1)*NPIX + p0);

  float tm[4] = {tm4.x,tm4.y,tm4.z,tm4.w};
  float lb[4] = {lb4.x,lb4.y,lb4.z,lb4.w};
  float ta_[16] = {tv0.x,tv0.y,tv0.z,tv0.w, tv1.x,tv1.y,tv1.z,tv1.w,
                   tv2.x,tv2.y,tv2.z,tv2.w, tv3.x,tv3.y,tv3.z,tv3.w};
  float xs_[16] = {xc0.x,xc0.y,xc0.z,xc0.w, xc1.x,xc1.y,xc1.z,xc1.w,
                   xc2.x,xc2.y,xc2.z,xc2.w, xc3.x,xc3.y,xc3.z,xc3.w};

  float pcf[4]={0,0,0,0}, ps[4]={0,0,0,0};
  unsigned zc[4]={0,0,0,0};
  float bce1=0.f, i1=0.f, x1s=0.f, t1s=0.f;
  float bce2=0.f, i2=0.f, x2s=0.f, t2s=0.f;

  #pragma unroll
  for (int ch=0; ch<4; ++ch){
    #pragma unroll
    for (int j=0;j<4;++j){
      float t = ta_[j*4+ch];
      float x = xs_[ch*4+j];
      float E = __expf(-fabsf(x));               // native v_exp
      float r = __builtin_amdgcn_rcpf(1.f+E);    // sigmoid(|x|)
      float s = (x>=0.f)? r : 1.f-r;             // sigmoid(x)
      float d = s - t;
      float v = d*d*tm[j];                       // pre_loss in [0,1)
      if (t >= 0.001f){ pcf[ch]+=1.f; ps[ch]+=v; }
      else {
        unsigned code = rtne16_(v);              // <= 0x3F80
        if (code == 0u) zc[ch]++;                // zero-class: registers
        else {
          unsigned fx = (unsigned)(v*1024.f + 0.5f);       // <= 1024
          atomicAdd(&s_hist[cpy + ch*NBIN + (int)(code>>6)],
                    (1u<<21) | fx);              // ONE packed u32 atomic
        }
      }
      if (ch==3){                                // seg2: last ch vs label
        float tt = lb[j];
        bce2 += fmaxf(x,0.f) - x*tt + __logf(1.f+E);
        i2 += s*tt; x2s += s; t2s += tt;
      }
    }
  }

  { // seg1: us channels vs one-hot(label)
    float aa[4]={ua4.x,ua4.y,ua4.z,ua4.w};
    float bb[4]={ub4.x,ub4.y,ub4.z,ub4.w};
    #pragma unroll
    for (int j=0;j<4;++j){
      float t1 = lb[j], t0 = 1.f - t1;
      float x0=aa[j], x1=bb[j];
      float E0 = __expf(-fabsf(x0)), E1 = __expf(-fabsf(x1));
      float r0 = __builtin_amdgcn_rcpf(1.f+E0);
      float r1 = __builtin_amdgcn_rcpf(1.f+E1);
      float s0 = (x0>=0.f)? r0 : 1.f-r0;
      float s1 = (x1>=0.f)? r1 : 1.f-r1;
      bce1 += fmaxf(x0,0.f) - x0*t0 + __logf(1.f+E0);
      bce1 += fmaxf(x1,0.f) - x1*t1 + __logf(1.f+E1);
      i1 += s0*t0 + s1*t1; x1s += s0+s1; t1s += t0+t1;
    }
  }

  #pragma unroll
  for (int ch=0;ch<4;++ch)
    if (zc[ch]) atomicAdd(&s_hist[cpy + ch*NBIN], zc[ch]<<21); // bin0: cnt only

  // 16-scalar block reduction (16 waves)
  __shared__ float s_red[16][16];
  float red[16] = {pcf[0],pcf[1],pcf[2],pcf[3], ps[0],ps[1],ps[2],ps[3],
                   bce1, i1, x1s, t1s, bce2, i2, x2s, t2s};
  int wid = tid>>6, lane = tid&63;
  #pragma unroll
  for (int q=0;q<16;++q){
    float r = wredf_(red[q]);
    if (lane==0) s_red[wid][q] = r;
  }
  __syncthreads();
  if (tid < 16){
    float tot = 0.f;
    #pragma unroll
    for (int w2=0;w2<16;++w2) tot += s_red[w2][tid];
    int q = tid;
    if      (q<4)   atomicAdd(&pos_cf[img*4+q], tot);
    else if (q<8)   atomicAdd(&pos_s[img*4+q-4], tot);
    else if (q==8)  atomicAdd(&segacc[0], tot);
    else if (q==9)  atomicAdd(&segacc[2+img], tot);
    else if (q==10) atomicAdd(&segacc[10+img], tot);
    else if (q==11) atomicAdd(&segacc[18+img], tot);
    else if (q==12) atomicAdd(&segacc[1], tot);
    else if (q==13) atomicAdd(&segacc[26+img], tot);
    else if (q==14) atomicAdd(&segacc[34+img], tot);
    else            atomicAdd(&segacc[42+img], tot);
  }

  // flush: ONE pass (1024 lanes x 1024 bins), unpack 16 copies
  {
    int j = tid;                                 // 0..1023 = [ch][bin]
    unsigned c=0u, fsum=0u;
    #pragma unroll
    for (int cp=0;cp<16;++cp){
      unsigned p = s_hist[cp*HSTR + j];
      c    += p>>21;
      fsum += p & 0x1FFFFFu;
    }
    int ch = j>>8, bin = j&255;
    if (c){
      atomicAdd(&ghc[(img*4+ch)*NBIN + bin], c);
      float s = (float)fsum * (1.f/1024.f);
      if (s!=0.f) atomicAdd(&ghs[(img*4+ch)*NBIN + bin], s);
    }
  }
}

// ---------------------------------------------------------------------------
// POST: items + scalar fused in ONE single-block launch (1024 threads).
// Each row owned by a 32-lane group (lane t: bins [t*8, t*8+8)); shfl-based
// suffix scan (width 32); owner lane applies the order-statistics boundary
// correction (R14..R21: absmax 0.0). Then wave 0 assembles the scalar.
// Output: (h<<16)|h dual f32/bf16 encoding (proven).
// ---------------------------------------------------------------------------
__global__ __launch_bounds__(1024) void k_post(
  const unsigned* __restrict__ ghc, const float* __restrict__ ghs,
  const float* __restrict__ pos_cf, const float* __restrict__ pos_s,
  const float* __restrict__ segacc, const float* __restrict__ swp,
  unsigned* __restrict__ out)
{
  __shared__ float s_items[NROWS];
  int tid = threadIdx.x;
  int row = tid >> 5, t32 = tid & 31;

  {
    unsigned pc = (unsigned)pos_cf[row];
    float psv = pos_s[row];
    unsigned neg = (unsigned)NPIX - pc, k3 = 3u*pc;
    unsigned k = pc ? (neg<k3?neg:k3) : 100u;   // pos==0 -> top-100 fallback

    unsigned bc[8]; float bsum=0.f; unsigned bcnt=0u;
    #pragma unroll
    for (int j=0;j<8;++j){
      int b = row*NBIN + t32*8 + j;
      bc[j] = ghc[b];
      bcnt += bc[j];
      bsum += ghs[b];
    }
    unsigned suf_c = bcnt; float suf_s = bsum;
    #pragma unroll
    for (int o=1;o<32;o<<=1){
      unsigned c2 = __shfl_down(suf_c, o, 32);
      float    s2 = __shfl_down(suf_s, o, 32);
      if (t32 + o < 32){ suf_c += c2; suf_s += s2; }
    }
    unsigned nxt_c = __shfl_down(suf_c, 1, 32);
    float    nxt_s = __shfl_down(suf_s, 1, 32);
    if (t32 == 31){ nxt_c = 0u; nxt_s = 0.f; }

    if (k == 0u){
      if (t32==0) s_items[row] = psv/(float)(pc?pc:1u);
    } else if (t32==0 && suf_c < k){
      float ssel = suf_s;                       // cut in zero-class tail
      s_items[row] = pc ? (psv/(float)pc + ssel/(float)k) : (ssel/100.f);
    } else if (nxt_c < k && suf_c >= k){        // owner lane
      unsigned cnt = nxt_c; float sum = nxt_s;
      int bin = -1; unsigned c0 = 1u; float sown = 0.f;
      for (int j=7;j>=0;--j){
        unsigned c = bc[j];
        if (!c) continue;
        if (cnt + c >= k){ bin = t32*8 + j; c0 = c;
                           sown = ghs[row*NBIN + bin]; break; }
        cnt += c; sum += ghs[row*NBIN + t32*8 + j];
      }
      unsigned rem = k - cnt;                   // 1 <= rem <= c0
      float mean = sown / (float)c0;
      float lo = __uint_as_float(((unsigned)bin<<6)<<16);
      float hi = __uint_as_float((((unsigned)bin+1u)<<6)<<16);
      float wdt = hi - lo;
      float mtop = mean + 0.5f*wdt*(1.f - (float)rem/(float)c0);
      mtop = fminf(fmaxf(mtop, lo), hi);        // safety clamp
      float ssel = sum + (float)rem * mtop;
      s_items[row] = pc ? (psv/(float)pc + ssel/(float)k) : (ssel/100.f);
    }
  }
  __syncthreads();
  if (tid >= 64) return;

  // ---- scalar assembly on wave 0 ----
  float v = (tid<NROWS)? s_items[tid] : 0.f;
  v = wredf_(v);                                 // lane 0 gets total
  if (tid != 0) return;

  double lsum = (double)v;
  double sw = (double)swp[0];
  double loss = (lsum/8.0)/(2.0*sw*sw + 1e-6) - log(sw);
  double d1=0.0, d2=0.0;
  for (int i=0;i<8;++i){
    d1 += (2.0*(double)segacc[2+i]  + 1e-5)/((double)segacc[10+i] + (double)segacc[18+i] + 1e-5);
    d2 += (2.0*(double)segacc[26+i] + 1e-5)/((double)segacc[34+i] + (double)segacc[42+i] + 1e-5);
  }
  double seg1 = 0.5*((double)segacc[0]/(2.0*8.0*(double)NPIX)) + (1.0 - d1/8.0);
  double seg2 = 0.5*((double)segacc[1]/(8.0*(double)NPIX))     + (1.0 - d2/8.0);
  float tot = (float)(seg1 + seg2 + loss);
  unsigned u = __float_as_uint(tot);
  unsigned h = (u + 0x7FFFu + ((u>>16)&1u)) >> 16;   // RTNE bf16 bits
  out[0] = (h<<16) | h;                               // dual f32/bf16 encoding
}

// ---------------------------------------------------------------------------
extern "C" void kernel_launch(void* const* d_in, const int* in_sizes, int n_in,
                              void* d_out, int out_size, void* d_ws, size_t ws_size,
                              hipStream_t stream)
{
  const float* us         = (const float*)d_in[0];  // (8,2,512,512)
  const float* inputs     = (const float*)d_in[1];  // (8,4,512,512)
  const float* train_mask = (const float*)d_in[2];  // (8,1,512,512)
  const float* tr_mask    = (const float*)d_in[3];  // (8,512,512,4)
  const float* label      = (const float*)d_in[4];  // (8,1,512,512)
  const float* sw         = (const float*)d_in[5];  // (1,)

  char* w = (char*)d_ws;
  size_t off = 0;
  unsigned* ghc   = (unsigned*)(w+off); off += (size_t)NROWS*NBIN*4;  // 32KB
  float*    ghs   = (float*)(w+off);    off += (size_t)NROWS*NBIN*4;  // 32KB
  float*    pos_cf= (float*)(w+off);    off += NROWS*4;
  float*    pos_s = (float*)(w+off);    off += NROWS*4;
  float*    segacc= (float*)(w+off);    off += 64*4;
  size_t zbytes = off;                               // ~66KB zeroed each call

  hipMemsetAsync(w, 0, zbytes, stream);

  k_mega <<<dim3(512),  dim3(1024), 0, stream>>>(us, inputs, train_mask, tr_mask,
                                                 label, ghc, ghs,
                                                 pos_cf, pos_s, segacc);
  k_post <<<dim3(1),    dim3(1024), 0, stream>>>(ghc, ghs, pos_cf, pos_s,
                                                 segacc, sw, (unsigned*)d_out);
}